// Round 5
// baseline (930.741 us; speedup 1.0000x reference)
//
#include <hip/hip_runtime.h>

// LowrankLearnableHash: 3x bilinear plane samples (12ch) -> elementwise product
// -> rank-4 sum to 3 coords -> trilinear sample of 32ch feature volume.
//
// R7 strategy (post-mortem of R6: payload buckets regressed; whole-pipeline
// compulsory traffic is ~480MB (~85us at BW) but we spend 361us -- the sort/
// stage machinery itself dominates. With transposed planeT (9.4MB) the plane
// taps are LLC-resident even in RANDOM order (~29M lines ~ 50us of L1-miss
// pipe), and the feature region is L1-hot regardless. So: DROP THE SORT.):
//  * prep_tr: just the two layout transposes (planes->[256,256,12],
//    features->[64,64,64,32]).
//  * lrh_fused: original point order, 4 pts/thread via 3 coalesced float4
//    reads, plane bilinear direct from planeT (LLC), feature trilinear from
//    featT (L1-hot), contiguous 512B/thread output writes. No LDS, no
//    atomics, no barriers; __launch_bounds__(256,4) for occupancy.

constexpr int kNPts   = 2000000;
constexpr int kReso   = 256;
constexpr int kPix    = kReso * kReso;        // 65536
constexpr int kCPlane = 12;                   // OUT_DIM(3) * RANK(4)
constexpr int kFReso  = 64;
constexpr int kNVox   = kFReso * kFReso * kFReso;  // 262144
constexpr int kFDim   = 32;

constexpr int kThreads     = 256;
constexpr int kPlaneBlocks = (3 * (kPix / 4)) / kThreads;   // 192
constexpr int kFeatBlocks  = (kNVox / 4) / kThreads;        // 256
constexpr int kPrepBlocks  = kPlaneBlocks + kFeatBlocks;    // 448

constexpr int kPtsPerTh  = 4;
constexpr int kMainThreadsTotal = kNPts / kPtsPerTh;        // 500000 (exact)
constexpr int kMainBlocks = (kMainThreadsTotal + kThreads - 1) / kThreads;  // 1954

static __device__ __forceinline__ float clampf(float v, float lo, float hi) {
  return fminf(fmaxf(v, lo), hi);
}

static __device__ __forceinline__ float4 f4_scale_add(float4 v, float s, float4 acc) {
  acc.x = fmaf(v.x, s, acc.x);
  acc.y = fmaf(v.y, s, acc.y);
  acc.z = fmaf(v.z, s, acc.z);
  acc.w = fmaf(v.w, s, acc.w);
  return acc;
}

// Bilinear from global transposed plane [256,256,12]. base = &plane[(r0*256+c0)*12].
// Same accumulation order as the verified sample_plane_tr (v00,v01,v10,v11).
static __device__ __forceinline__ void bilin_g(
    const float* __restrict__ base, float wc, float wr, float4 r[3]) {
  float w00 = (1.0f - wc) * (1.0f - wr);
  float w01 = wc * (1.0f - wr);
  float w10 = (1.0f - wc) * wr;
  float w11 = wc * wr;
  const float4* t00 = (const float4*)base;
  const float4* t01 = (const float4*)(base + kCPlane);
  const float4* t10 = (const float4*)(base + kReso * kCPlane);
  const float4* t11 = (const float4*)(base + kReso * kCPlane + kCPlane);
#pragma unroll
  for (int i = 0; i < 3; ++i) {
    float4 acc = make_float4(0.f, 0.f, 0.f, 0.f);
    acc = f4_scale_add(t00[i], w00, acc);
    acc = f4_scale_add(t01[i], w01, acc);
    acc = f4_scale_add(t10[i], w10, acc);
    acc = f4_scale_add(t11[i], w11, acc);
    r[i] = acc;
  }
}

// ---------------- prep: the two layout transposes ----------------

__global__ __launch_bounds__(256) void prep_tr(
    const float* __restrict__ p0, const float* __restrict__ p1,
    const float* __restrict__ p2, const float* __restrict__ featSrc,
    float* __restrict__ planeT, float* __restrict__ featT) {
  int b = blockIdx.x;
  int tid = threadIdx.x;

  if (b < kPlaneBlocks) {
    // --- 3 planes [12,256,256] -> planeT: 3 x [256,256,12]; 4 px/thread ---
    int t = b * kThreads + tid;
    constexpr int quarter = kPix / 4;  // 16384
    int p = t / quarter;
    int pix4 = (t % quarter) * 4;
    const float* src = (p == 0) ? p0 : (p == 1) ? p1 : p2;
    float4 v[kCPlane];
#pragma unroll
    for (int c = 0; c < kCPlane; ++c)
      v[c] = *(const float4*)(src + (size_t)c * kPix + pix4);
    float* dstb = planeT + ((size_t)p * kPix + pix4) * kCPlane;
#pragma unroll
    for (int j = 0; j < 4; ++j) {
      float e[kCPlane];
#pragma unroll
      for (int c = 0; c < kCPlane; ++c) {
        const float* vc = (const float*)&v[c];
        e[c] = vc[j];
      }
      float4* dst = (float4*)(dstb + (size_t)j * kCPlane);
      dst[0] = make_float4(e[0], e[1], e[2], e[3]);
      dst[1] = make_float4(e[4], e[5], e[6], e[7]);
      dst[2] = make_float4(e[8], e[9], e[10], e[11]);
    }
  } else {
    // --- features [32,64,64,64] -> featT [64,64,64,32]; 4 vox/thread ---
    int t = (b - kPlaneBlocks) * kThreads + tid;
    int vox4 = t * 4;
#pragma unroll
    for (int chunk = 0; chunk < 4; ++chunk) {
      float4 v[8];
#pragma unroll
      for (int c8 = 0; c8 < 8; ++c8) {
        int c = chunk * 8 + c8;
        v[c8] = *(const float4*)(featSrc + (size_t)c * kNVox + vox4);
      }
#pragma unroll
      for (int j = 0; j < 4; ++j) {
        float e[8];
#pragma unroll
        for (int c8 = 0; c8 < 8; ++c8) e[c8] = ((const float*)&v[c8])[j];
        float4* dst = (float4*)(featT + (size_t)(vox4 + j) * kFDim + chunk * 8);
        dst[0] = make_float4(e[0], e[1], e[2], e[3]);
        dst[1] = make_float4(e[4], e[5], e[6], e[7]);
      }
    }
  }
}

// ---------------- fused main: original order, no sort ----------------

__global__ __launch_bounds__(256, 4) void lrh_fused(
    const float* __restrict__ pts, const float* __restrict__ planeT,
    const float* __restrict__ feat, float* __restrict__ out) {
  int t = blockIdx.x * blockDim.x + threadIdx.x;
  if (t >= kMainThreadsTotal) return;

  // 4 consecutive points per thread via 3 coalesced float4 loads
  const float4* p4 = (const float4*)(pts + (size_t)t * 12);
  float4 q0 = p4[0], q1 = p4[1], q2 = p4[2];
  float xs[4] = {q0.x, q0.w, q1.z, q2.y};
  float ys[4] = {q0.y, q1.x, q1.w, q2.z};
  float zs[4] = {q0.z, q1.y, q2.x, q2.w};

  const float* p01 = planeT;
  const float* p02 = planeT + (size_t)kPix * kCPlane;
  const float* p12 = planeT + (size_t)2 * kPix * kCPlane;

  for (int j = 0; j < 4; ++j) {
    float xx = xs[j], yy = ys[j], zz = zs[j];

    // per-axis pixel coords (shared by the two planes using that axis)
    float px = clampf((xx + 1.0f) * 0.5f * (float)(kReso - 1), 0.0f, (float)(kReso - 1));
    float py = clampf((yy + 1.0f) * 0.5f * (float)(kReso - 1), 0.0f, (float)(kReso - 1));
    float pz = clampf((zz + 1.0f) * 0.5f * (float)(kReso - 1), 0.0f, (float)(kReso - 1));
    float fx0 = fminf(floorf(px), (float)(kReso - 2));
    float fy0 = fminf(floorf(py), (float)(kReso - 2));
    float fz0 = fminf(floorf(pz), (float)(kReso - 2));
    int ix = (int)fx0;
    int iy = (int)fy0;
    int iz = (int)fz0;
    float wx = px - fx0, wy = py - fy0, wz = pz - fz0;

    float4 a[3], bb[3], c3[3];
    bilin_g(p01 + (size_t)(iy * kReso + ix) * kCPlane, wx, wy, a);    // (x,y)
    bilin_g(p02 + (size_t)(iz * kReso + ix) * kCPlane, wx, wz, bb);   // (x,z)
    bilin_g(p12 + (size_t)(iz * kReso + iy) * kCPlane, wy, wz, c3);   // (y,z)

    float coord[3];
#pragma unroll
    for (int d = 0; d < 3; ++d) {
      float mx = a[d].x * bb[d].x * c3[d].x;
      float my = a[d].y * bb[d].y * c3[d].y;
      float mz = a[d].z * bb[d].z * c3[d].z;
      float mw = a[d].w * bb[d].w * c3[d].w;
      coord[d] = (mx + my) + (mz + mw);
    }

    float gx = clampf((coord[0] + 1.0f) * 0.5f * (float)(kFReso - 1), 0.0f, (float)(kFReso - 1));
    float gy = clampf((coord[1] + 1.0f) * 0.5f * (float)(kFReso - 1), 0.0f, (float)(kFReso - 1));
    float gz = clampf((coord[2] + 1.0f) * 0.5f * (float)(kFReso - 1), 0.0f, (float)(kFReso - 1));
    float gfx0 = fminf(floorf(gx), (float)(kFReso - 2));
    float gfy0 = fminf(floorf(gy), (float)(kFReso - 2));
    float gfz0 = fminf(floorf(gz), (float)(kFReso - 2));
    int ix0 = (int)gfx0;
    int iy0 = (int)gfy0;
    int iz0 = (int)gfz0;
    float fwx = gx - gfx0, fwy = gy - gfy0, fwz = gz - gfz0;

    float acc[kFDim];
#pragma unroll
    for (int c = 0; c < kFDim; ++c) acc[c] = 0.0f;

#pragma unroll
    for (int dz = 0; dz < 2; ++dz) {
      float fzw = dz ? fwz : (1.0f - fwz);
#pragma unroll
      for (int dy = 0; dy < 2; ++dy) {
        float fyw = dy ? fwy : (1.0f - fwy);
#pragma unroll
        for (int dx = 0; dx < 2; ++dx) {
          float w = fzw * fyw * (dx ? fwx : (1.0f - fwx));
          int vox = ((iz0 + dz) * kFReso + (iy0 + dy)) * kFReso + (ix0 + dx);
          const float4* v = (const float4*)(feat + (size_t)vox * kFDim);
#pragma unroll
          for (int k = 0; k < 8; ++k) {
            float4 tv = v[k];
            acc[4 * k + 0] = fmaf(tv.x, w, acc[4 * k + 0]);
            acc[4 * k + 1] = fmaf(tv.y, w, acc[4 * k + 1]);
            acc[4 * k + 2] = fmaf(tv.z, w, acc[4 * k + 2]);
            acc[4 * k + 3] = fmaf(tv.w, w, acc[4 * k + 3]);
          }
        }
      }
    }

    size_t n = (size_t)t * kPtsPerTh + j;
    float4* o = (float4*)(out + n * kFDim);
#pragma unroll
    for (int k = 0; k < 8; ++k)
      o[k] = make_float4(acc[4 * k], acc[4 * k + 1], acc[4 * k + 2], acc[4 * k + 3]);
  }
}

extern "C" void kernel_launch(void* const* d_in, const int* in_sizes, int n_in,
                              void* d_out, int out_size, void* d_ws, size_t ws_size,
                              hipStream_t stream) {
  const float* pts  = (const float*)d_in[0];
  const float* p01  = (const float*)d_in[1];
  const float* p02  = (const float*)d_in[2];
  const float* p12  = (const float*)d_in[3];
  const float* feat = (const float*)d_in[4];
  float* out = (float*)d_out;

  // workspace layout: just the two transposed tensors (~43 MB)
  const size_t off_planeT = 0;
  const size_t sz_planeT  = (size_t)3 * kPix * kCPlane * sizeof(float);   // 9,437,184
  const size_t off_featT  = off_planeT + sz_planeT;
  const size_t sz_featT   = (size_t)kNVox * kFDim * sizeof(float);        // 33,554,432
  const size_t need = off_featT + sz_featT;                               // ~43 MB

  if (ws_size < need) return;

  char* wsb = (char*)d_ws;
  float* planeT = (float*)(wsb + off_planeT);
  float* featT  = (float*)(wsb + off_featT);

  hipLaunchKernelGGL(prep_tr, dim3(kPrepBlocks), dim3(kThreads), 0, stream,
                     p01, p02, p12, feat, planeT, featT);
  hipLaunchKernelGGL(lrh_fused, dim3(kMainBlocks), dim3(kThreads), 0, stream,
                     pts, planeT, featT, out);
}

// Round 6
// 489.006 us; speedup vs baseline: 1.9033x; 1.9033x over previous
//
#include <hip/hip_runtime.h>

// LowrankLearnableHash: 3x bilinear plane samples (12ch) -> elementwise product
// -> rank-4 sum to 3 coords -> trilinear sample of 32ch feature volume.
//
// R8 strategy (post-mortem of R7: unsorted plane taps = 1.9GB L2-miss traffic,
// 650us -- the sort IS load-bearing. Revert to R5 structure and fix its two
// measured bottlenecks):
//  * lrh_cells: dense chunks (R5) + octet-cooperative feature gather/store
//    (R3-verified): 8 lanes per point, lane l owns channels 4l..4l+3, so each
//    trilinear tap is ONE instr covering 8pts x 128B contiguous (16 L1
//    line-lookups/instr vs 64 in per-lane mode), and each output row is one
//    128B store. Octet o at step s handles point step*32+o -> the s_* LDS
//    reads are conflict-free (consecutive addresses across octets).
//  * prep_fused: same algorithm at 1024 thr/block -> 16 waves/CU on scatter
//    CUs (was 4) to hide global-atomic + scattered-write latency.

constexpr int kNPts   = 2000000;
constexpr int kReso   = 256;
constexpr int kPix    = kReso * kReso;        // 65536
constexpr int kCPlane = 12;                   // OUT_DIM(3) * RANK(4)
constexpr int kFReso  = 64;
constexpr int kNVox   = kFReso * kFReso * kFReso;  // 262144
constexpr int kFDim   = 32;
constexpr int kCellRes = 16;                  // bucket grid per axis
constexpr int kNCell  = kCellRes * kCellRes * kCellRes;  // 4096
constexpr int kCap    = 640;                  // slots per cell (mean 488)
constexpr unsigned kOvCap = 2000000u;         // overflow list (full N: can never drop)

constexpr int kThreads     = 256;             // lrh block size
constexpr int kPrepThreads = 1024;            // prep block size
constexpr int kPtsPerScB   = 16384;           // points per scatter block
constexpr int kScBlocks    = (kNPts + kPtsPerScB - 1) / kPtsPerScB;     // 123
constexpr int kPlaneBlocks = (3 * (kPix / 4)) / kPrepThreads;           // 48
constexpr int kFeatBlocks  = (kNVox / 4) / kPrepThreads;                // 64
constexpr int kPrepBlocks  = kScBlocks + kPlaneBlocks + kFeatBlocks;    // 235
constexpr int kOvBlocks    = 16;

constexpr int kStage = 18;                    // staged rows/cols per plane region
constexpr int kRowF  = kStage * kCPlane;      // 216 floats per staged row

static __device__ __forceinline__ float clampf(float v, float lo, float hi) {
  return fminf(fmaxf(v, lo), hi);
}

static __device__ __forceinline__ float4 f4_scale_add(float4 v, float s, float4 acc) {
  acc.x = fmaf(v.x, s, acc.x);
  acc.y = fmaf(v.y, s, acc.y);
  acc.z = fmaf(v.z, s, acc.z);
  acc.w = fmaf(v.w, s, acc.w);
  return acc;
}

static __device__ __forceinline__ int cell_of(float x, float y, float z) {
  int xq = min(kCellRes - 1, max(0, (int)((x + 1.0f) * (0.5f * kCellRes))));
  int yq = min(kCellRes - 1, max(0, (int)((y + 1.0f) * (0.5f * kCellRes))));
  int zq = min(kCellRes - 1, max(0, (int)((z + 1.0f) * (0.5f * kCellRes))));
  return (zq * kCellRes + yq) * kCellRes + xq;
}

// Bilinear sample of transposed plane [256,256,12] from GLOBAL (overflow path).
static __device__ __forceinline__ void sample_plane_tr(
    const float* __restrict__ plane, float cx, float cy, float4 r[3]) {
  float x = clampf((cx + 1.0f) * 0.5f * (float)(kReso - 1), 0.0f, (float)(kReso - 1));
  float y = clampf((cy + 1.0f) * 0.5f * (float)(kReso - 1), 0.0f, (float)(kReso - 1));
  float fx0 = fminf(floorf(x), (float)(kReso - 2));
  float fy0 = fminf(floorf(y), (float)(kReso - 2));
  int x0 = (int)fx0;
  int y0 = (int)fy0;
  float wx = x - fx0;
  float wy = y - fy0;
  float w00 = (1.0f - wx) * (1.0f - wy);
  float w01 = wx * (1.0f - wy);
  float w10 = (1.0f - wx) * wy;
  float w11 = wx * wy;
  const float4* v00 = (const float4*)(plane + (size_t)(y0 * kReso + x0) * kCPlane);
  const float4* v01 = (const float4*)(plane + (size_t)(y0 * kReso + x0 + 1) * kCPlane);
  const float4* v10 = (const float4*)(plane + (size_t)((y0 + 1) * kReso + x0) * kCPlane);
  const float4* v11 = (const float4*)(plane + (size_t)((y0 + 1) * kReso + x0 + 1) * kCPlane);
#pragma unroll
  for (int i = 0; i < 3; ++i) {
    float4 acc = make_float4(0.f, 0.f, 0.f, 0.f);
    acc = f4_scale_add(v00[i], w00, acc);
    acc = f4_scale_add(v01[i], w01, acc);
    acc = f4_scale_add(v10[i], w10, acc);
    acc = f4_scale_add(v11[i], w11, acc);
    r[i] = acc;
  }
}

// Bilinear from an LDS-staged [18][18][12] region.
static __device__ __forceinline__ void bilin_lds(
    const float* __restrict__ sp, int lc, int lr, float wc, float wr, float4 r[3]) {
  const float* t00 = sp + (lr * kStage + lc) * kCPlane;
  const float* t01 = t00 + kCPlane;
  const float* t10 = t00 + kRowF;
  const float* t11 = t10 + kCPlane;
  float w00 = (1.0f - wc) * (1.0f - wr);
  float w01 = wc * (1.0f - wr);
  float w10 = (1.0f - wc) * wr;
  float w11 = wc * wr;
#pragma unroll
  for (int i = 0; i < 3; ++i) {
    float4 acc = make_float4(0.f, 0.f, 0.f, 0.f);
    acc = f4_scale_add(((const float4*)t00)[i], w00, acc);
    acc = f4_scale_add(((const float4*)t01)[i], w01, acc);
    acc = f4_scale_add(((const float4*)t10)[i], w10, acc);
    acc = f4_scale_add(((const float4*)t11)[i], w11, acc);
    r[i] = acc;
  }
}

// ---------------- fused prep: two-pass bucket scatter + both transposes ----------------

__global__ __launch_bounds__(1024) void prep_fused(
    const float* __restrict__ pts,
    const float* __restrict__ p0, const float* __restrict__ p1,
    const float* __restrict__ p2, const float* __restrict__ featSrc,
    float* __restrict__ planeT, float* __restrict__ featT,
    unsigned* __restrict__ counts, unsigned* __restrict__ ovcnt,
    unsigned* __restrict__ ovlist, unsigned* __restrict__ buckets) {
  __shared__ unsigned short s_cellid[kPtsPerScB];  // 32 KB
  __shared__ unsigned s_hist[kNCell];              // 16 KB (count -> block base)
  __shared__ unsigned s_loc[kNCell];               // 16 KB (local rank)

  int b = blockIdx.x;
  int tid = threadIdx.x;

  if (b < kScBlocks) {
    // ---- block-local two-pass counting scatter over 16K points ----
    for (int i = tid; i < kNCell; i += kPrepThreads) s_hist[i] = 0u;
    __syncthreads();

    size_t base = (size_t)b * kPtsPerScB;
    // pass 1: cell ids + LDS histogram (16 iterations)
    for (int k = 0; k < kPtsPerScB / kPrepThreads; ++k) {
      int sl = k * kPrepThreads + tid;
      size_t g = base + sl;
      unsigned short cid = 0xFFFFu;
      if (g < (size_t)kNPts) {
        const float* pp = pts + 3 * g;
        cid = (unsigned short)cell_of(pp[0], pp[1], pp[2]);
        atomicAdd(&s_hist[cid], 1u);
      }
      s_cellid[sl] = cid;
    }
    __syncthreads();

    // reservation: one global atomic per nonempty cell; zero local ranks
    for (int c = tid; c < kNCell; c += kPrepThreads) {
      unsigned h = s_hist[c];
      s_loc[c] = 0u;
      s_hist[c] = h ? atomicAdd(&counts[c], h) : 0u;
    }
    __syncthreads();

    // pass 2: replay cell ids, write bucket indices in per-block runs
    for (int k = 0; k < kPtsPerScB / kPrepThreads; ++k) {
      int sl = k * kPrepThreads + tid;
      unsigned short cid = s_cellid[sl];
      if (cid == 0xFFFFu) continue;
      unsigned r = atomicAdd(&s_loc[cid], 1u);
      unsigned pos = s_hist[cid] + r;
      unsigned idx = (unsigned)(base + sl);
      if (pos < (unsigned)kCap) {
        buckets[(size_t)cid * kCap + pos] = idx;
      } else {
        unsigned op = atomicAdd(ovcnt, 1u);
        if (op < kOvCap) ovlist[op] = idx;
      }
    }
  } else if (b < kScBlocks + kPlaneBlocks) {
    // --- 3 planes [12,256,256] -> planeT: 3 x [256,256,12]; 4 px/thread ---
    int t = (b - kScBlocks) * kPrepThreads + tid;
    constexpr int quarter = kPix / 4;  // 16384
    int p = t / quarter;
    int pix4 = (t % quarter) * 4;
    const float* src = (p == 0) ? p0 : (p == 1) ? p1 : p2;
    float4 v[kCPlane];
#pragma unroll
    for (int c = 0; c < kCPlane; ++c)
      v[c] = *(const float4*)(src + (size_t)c * kPix + pix4);
    float* dstb = planeT + ((size_t)p * kPix + pix4) * kCPlane;
#pragma unroll
    for (int j = 0; j < 4; ++j) {
      float e[kCPlane];
#pragma unroll
      for (int c = 0; c < kCPlane; ++c) {
        const float* vc = (const float*)&v[c];
        e[c] = vc[j];
      }
      float4* dst = (float4*)(dstb + (size_t)j * kCPlane);
      dst[0] = make_float4(e[0], e[1], e[2], e[3]);
      dst[1] = make_float4(e[4], e[5], e[6], e[7]);
      dst[2] = make_float4(e[8], e[9], e[10], e[11]);
    }
  } else {
    // --- features [32,64,64,64] -> featT [64,64,64,32]; 4 vox/thread ---
    int t = (b - kScBlocks - kPlaneBlocks) * kPrepThreads + tid;
    int vox4 = t * 4;
#pragma unroll
    for (int chunk = 0; chunk < 4; ++chunk) {
      float4 v[8];
#pragma unroll
      for (int c8 = 0; c8 < 8; ++c8) {
        int c = chunk * 8 + c8;
        v[c8] = *(const float4*)(featSrc + (size_t)c * kNVox + vox4);
      }
#pragma unroll
      for (int j = 0; j < 4; ++j) {
        float e[8];
#pragma unroll
        for (int c8 = 0; c8 < 8; ++c8) e[c8] = ((const float*)&v[c8])[j];
        float4* dst = (float4*)(featT + (size_t)(vox4 + j) * kFDim + chunk * 8);
        dst[0] = make_float4(e[0], e[1], e[2], e[3]);
        dst[1] = make_float4(e[4], e[5], e[6], e[7]);
      }
    }
  }
}

// ---------------- main kernel: one 16^3 cell per block ----------------

__global__ __launch_bounds__(256) void lrh_cells(
    const float* __restrict__ pts, const float* __restrict__ planeT,
    const float* __restrict__ feat,
    const unsigned* __restrict__ counts, const unsigned* __restrict__ buckets,
    const unsigned* __restrict__ ovcnt, const unsigned* __restrict__ ovlist,
    float* __restrict__ out) {
  __shared__ float s_plane[3][kStage * kRowF];  // 46656 B
  __shared__ int   s_n[kThreads];               // 1 KB
  __shared__ int   s_vox[kThreads];             // 1 KB
  __shared__ float s_wx[kThreads];              // 1 KB
  __shared__ float s_wy[kThreads];              // 1 KB
  __shared__ float s_wz[kThreads];              // 1 KB   -> total 51776 B

  int b = blockIdx.x;
  int tid = threadIdx.x;

  if (b < kNCell) {
    int cellx = b & (kCellRes - 1);
    int celly = (b >> 4) & (kCellRes - 1);
    int cellz = b >> 8;
    int sx = min(cellx * 255 / 16, kReso - kStage);
    int sy = min(celly * 255 / 16, kReso - kStage);
    int sz = min(cellz * 255 / 16, kReso - kStage);
    // plane01: cols=x rows=y; plane02: cols=x rows=z; plane12: cols=y rows=z
    const int colS[3] = {sx, sx, sy};
    const int rowS[3] = {sy, sz, sz};

#pragma unroll
    for (int p = 0; p < 3; ++p) {
      const float* src = planeT + (size_t)p * kPix * kCPlane;
      float* dst = s_plane[p];
      for (int i = tid; i < kStage * (kRowF / 4); i += kThreads) {  // 18*54
        int r = i / (kRowF / 4);
        int q = i - r * (kRowF / 4);
        float4 v = *(const float4*)(src +
            ((size_t)(rowS[p] + r) * kReso + colS[p]) * kCPlane + q * 4);
        *(float4*)(dst + r * kRowF + q * 4) = v;
      }
    }
    __syncthreads();

    unsigned craw = counts[b];
    int cnt = craw < (unsigned)kCap ? (int)craw : kCap;

    for (int base = 0; base < cnt; base += kThreads) {
      // ---------- phase 1: per-lane plane sampling -> LDS ----------
      int slot = base + tid;
      int n = -1;
      int ivox = 0;
      float wxo = 0.f, wyo = 0.f, wzo = 0.f;
      if (slot < cnt) {
        n = (int)buckets[(size_t)b * kCap + slot];
        const float* pp = pts + 3 * (size_t)n;
        float xx = pp[0], yy = pp[1], zz = pp[2];

        float px = clampf((xx + 1.0f) * 0.5f * (float)(kReso - 1), 0.0f, (float)(kReso - 1));
        float py = clampf((yy + 1.0f) * 0.5f * (float)(kReso - 1), 0.0f, (float)(kReso - 1));
        float pz = clampf((zz + 1.0f) * 0.5f * (float)(kReso - 1), 0.0f, (float)(kReso - 1));
        float fx0 = fminf(floorf(px), (float)(kReso - 2));
        float fy0 = fminf(floorf(py), (float)(kReso - 2));
        float fz0 = fminf(floorf(pz), (float)(kReso - 2));
        float wx = px - fx0, wy = py - fy0, wz = pz - fz0;
        int lx = min(max((int)fx0 - sx, 0), kStage - 2);
        int ly = min(max((int)fy0 - sy, 0), kStage - 2);
        int lz = min(max((int)fz0 - sz, 0), kStage - 2);

        float4 a[3], bb[3], c3[3];
        bilin_lds(s_plane[0], lx, ly, wx, wy, a);    // (x,y)
        bilin_lds(s_plane[1], lx, lz, wx, wz, bb);   // (x,z)
        bilin_lds(s_plane[2], ly, lz, wy, wz, c3);   // (y,z)

        float coord[3];
#pragma unroll
        for (int d = 0; d < 3; ++d) {
          float mx = a[d].x * bb[d].x * c3[d].x;
          float my = a[d].y * bb[d].y * c3[d].y;
          float mz = a[d].z * bb[d].z * c3[d].z;
          float mw = a[d].w * bb[d].w * c3[d].w;
          coord[d] = (mx + my) + (mz + mw);
        }

        float gx = clampf((coord[0] + 1.0f) * 0.5f * (float)(kFReso - 1), 0.0f, (float)(kFReso - 1));
        float gy = clampf((coord[1] + 1.0f) * 0.5f * (float)(kFReso - 1), 0.0f, (float)(kFReso - 1));
        float gz = clampf((coord[2] + 1.0f) * 0.5f * (float)(kFReso - 1), 0.0f, (float)(kFReso - 1));
        float gfx0 = fminf(floorf(gx), (float)(kFReso - 2));
        float gfy0 = fminf(floorf(gy), (float)(kFReso - 2));
        float gfz0 = fminf(floorf(gz), (float)(kFReso - 2));
        int ix0 = (int)gfx0;
        int iy0 = (int)gfy0;
        int iz0 = (int)gfz0;
        wxo = gx - gfx0;
        wyo = gy - gfy0;
        wzo = gz - gfz0;
        ivox = (iz0 * kFReso + iy0) * kFReso + ix0;
      }
      s_n[tid] = n;
      s_vox[tid] = ivox;
      s_wx[tid] = wxo;
      s_wy[tid] = wyo;
      s_wz[tid] = wzo;
      __syncthreads();

      // ---------- phase 2: octet-cooperative trilinear gather ----------
      // octet o = tid>>3 handles point step*32+o -> conflict-free s_* reads;
      // lane l = tid&7 owns channels 4l..4l+3 (one 128B-coalesced tap/instr).
      int l4 = (tid & 7) * 4;
      int oct = tid >> 3;  // 0..31
      for (int step = 0; step < 8; ++step) {
        int s = step * 32 + oct;
        int n2 = s_n[s];
        if (n2 < 0) continue;
        int vox = s_vox[s];
        float wx2 = s_wx[s], wy2 = s_wy[s], wz2 = s_wz[s];
        float ux = 1.0f - wx2, uy = 1.0f - wy2, uz = 1.0f - wz2;

        const float* fb = feat + (size_t)vox * kFDim + l4;
        float4 t0 = *(const float4*)(fb);
        float4 t1 = *(const float4*)(fb + kFDim);
        float4 t2 = *(const float4*)(fb + kFReso * kFDim);
        float4 t3 = *(const float4*)(fb + kFReso * kFDim + kFDim);
        float4 t4 = *(const float4*)(fb + kFReso * kFReso * kFDim);
        float4 t5 = *(const float4*)(fb + kFReso * kFReso * kFDim + kFDim);
        float4 t6 = *(const float4*)(fb + kFReso * kFReso * kFDim + kFReso * kFDim);
        float4 t7 = *(const float4*)(fb + kFReso * kFReso * kFDim + kFReso * kFDim + kFDim);

        float a0 = uz * uy, a1 = uz * wy2, a2 = wz2 * uy, a3 = wz2 * wy2;
        float w0 = a0 * ux, w1 = a0 * wx2;
        float w2 = a1 * ux, w3 = a1 * wx2;
        float w4 = a2 * ux, w5 = a2 * wx2;
        float w6 = a3 * ux, w7 = a3 * wx2;

        float4 acc;
        acc.x = t0.x * w0; acc.y = t0.y * w0; acc.z = t0.z * w0; acc.w = t0.w * w0;
        acc = f4_scale_add(t1, w1, acc);
        acc = f4_scale_add(t2, w2, acc);
        acc = f4_scale_add(t3, w3, acc);
        acc = f4_scale_add(t4, w4, acc);
        acc = f4_scale_add(t5, w5, acc);
        acc = f4_scale_add(t6, w6, acc);
        acc = f4_scale_add(t7, w7, acc);

        *(float4*)(out + (size_t)n2 * kFDim + l4) = acc;
      }
      __syncthreads();
    }
  } else {
    // ---------- overflow tail (expected ~0 points): per-lane full path ----------
    unsigned ov = *ovcnt;
    if (ov > kOvCap) ov = kOvCap;
    const float* p01 = planeT;
    const float* p02 = planeT + (size_t)kPix * kCPlane;
    const float* p12 = planeT + (size_t)2 * kPix * kCPlane;
    for (unsigned i = (unsigned)(b - kNCell) * kThreads + tid; i < ov;
         i += (unsigned)kOvBlocks * kThreads) {
      int n = (int)ovlist[i];
      float cx = pts[3 * (size_t)n + 0];
      float cy = pts[3 * (size_t)n + 1];
      float cz = pts[3 * (size_t)n + 2];

      float4 a[3], bb[3], c3[3];
      sample_plane_tr(p01, cx, cy, a);
      sample_plane_tr(p02, cx, cz, bb);
      sample_plane_tr(p12, cy, cz, c3);

      float coord[3];
#pragma unroll
      for (int d = 0; d < 3; ++d) {
        float mx = a[d].x * bb[d].x * c3[d].x;
        float my = a[d].y * bb[d].y * c3[d].y;
        float mz = a[d].z * bb[d].z * c3[d].z;
        float mw = a[d].w * bb[d].w * c3[d].w;
        coord[d] = (mx + my) + (mz + mw);
      }

      float gx = clampf((coord[0] + 1.0f) * 0.5f * (float)(kFReso - 1), 0.0f, (float)(kFReso - 1));
      float gy = clampf((coord[1] + 1.0f) * 0.5f * (float)(kFReso - 1), 0.0f, (float)(kFReso - 1));
      float gz = clampf((coord[2] + 1.0f) * 0.5f * (float)(kFReso - 1), 0.0f, (float)(kFReso - 1));
      float fx0 = fminf(floorf(gx), (float)(kFReso - 2));
      float fy0 = fminf(floorf(gy), (float)(kFReso - 2));
      float fz0 = fminf(floorf(gz), (float)(kFReso - 2));
      int ix0 = (int)fx0;
      int iy0 = (int)fy0;
      int iz0 = (int)fz0;
      float wx = gx - fx0, wy = gy - fy0, wz = gz - fz0;

      float acc[kFDim];
#pragma unroll
      for (int c = 0; c < kFDim; ++c) acc[c] = 0.0f;
#pragma unroll
      for (int dz = 0; dz < 2; ++dz) {
        float fzw = dz ? wz : (1.0f - wz);
#pragma unroll
        for (int dy = 0; dy < 2; ++dy) {
          float fyw = dy ? wy : (1.0f - wy);
#pragma unroll
          for (int dx = 0; dx < 2; ++dx) {
            float w = fzw * fyw * (dx ? wx : (1.0f - wx));
            int vox = ((iz0 + dz) * kFReso + (iy0 + dy)) * kFReso + (ix0 + dx);
            const float4* v = (const float4*)(feat + (size_t)vox * kFDim);
#pragma unroll
            for (int k = 0; k < 8; ++k) {
              float4 t = v[k];
              acc[4 * k + 0] = fmaf(t.x, w, acc[4 * k + 0]);
              acc[4 * k + 1] = fmaf(t.y, w, acc[4 * k + 1]);
              acc[4 * k + 2] = fmaf(t.z, w, acc[4 * k + 2]);
              acc[4 * k + 3] = fmaf(t.w, w, acc[4 * k + 3]);
            }
          }
        }
      }
      float4* o = (float4*)(out + (size_t)n * kFDim);
#pragma unroll
      for (int k = 0; k < 8; ++k)
        o[k] = make_float4(acc[4 * k], acc[4 * k + 1], acc[4 * k + 2], acc[4 * k + 3]);
    }
  }
}

extern "C" void kernel_launch(void* const* d_in, const int* in_sizes, int n_in,
                              void* d_out, int out_size, void* d_ws, size_t ws_size,
                              hipStream_t stream) {
  const float* pts  = (const float*)d_in[0];
  const float* p01  = (const float*)d_in[1];
  const float* p02  = (const float*)d_in[2];
  const float* p12  = (const float*)d_in[3];
  const float* feat = (const float*)d_in[4];
  float* out = (float*)d_out;

  // workspace layout
  const size_t off_planeT  = 0;
  const size_t sz_planeT   = (size_t)3 * kPix * kCPlane * sizeof(float);   // 9,437,184
  const size_t off_featT   = off_planeT + sz_planeT;
  const size_t sz_featT    = (size_t)kNVox * kFDim * sizeof(float);        // 33,554,432
  const size_t off_counts  = off_featT + sz_featT;
  const size_t sz_counts   = (size_t)kNCell * sizeof(unsigned);            // 16,384
  const size_t off_ovcnt   = off_counts + sz_counts;
  const size_t sz_ovcnt    = 256;
  const size_t off_ovlist  = off_ovcnt + sz_ovcnt;
  const size_t sz_ovlist   = (size_t)kOvCap * sizeof(unsigned);            // 8,000,000
  const size_t off_buckets = off_ovlist + sz_ovlist;
  const size_t sz_buckets  = (size_t)kNCell * kCap * sizeof(unsigned);     // 10,485,760
  const size_t need = off_buckets + sz_buckets;                            // ~61.5 MB

  if (ws_size < need) return;

  char* wsb = (char*)d_ws;
  float*    planeT  = (float*)(wsb + off_planeT);
  float*    featT   = (float*)(wsb + off_featT);
  unsigned* counts  = (unsigned*)(wsb + off_counts);
  unsigned* ovcnt   = (unsigned*)(wsb + off_ovcnt);
  unsigned* ovlist  = (unsigned*)(wsb + off_ovlist);
  unsigned* buckets = (unsigned*)(wsb + off_buckets);

  hipMemsetAsync(counts, 0, sz_counts + sz_ovcnt, stream);
  hipLaunchKernelGGL(prep_fused, dim3(kPrepBlocks), dim3(kPrepThreads), 0, stream,
                     pts, p01, p02, p12, feat, planeT, featT,
                     counts, ovcnt, ovlist, buckets);
  hipLaunchKernelGGL(lrh_cells, dim3(kNCell + kOvBlocks), dim3(kThreads), 0, stream,
                     pts, planeT, featT, counts, buckets, ovcnt, ovlist, out);
}

// Round 7
// 443.419 us; speedup vs baseline: 2.0990x; 1.1028x over previous
//
#include <hip/hip_runtime.h>
#include <hip/hip_fp16.h>

// LowrankLearnableHash: 3x bilinear plane samples (12ch) -> elementwise product
// -> rank-4 sum to 3 coords -> trilinear sample of 32ch feature volume.
//
// R9 strategy (R8 worked: both kernels now below the harness fill-wall; R5
// counters showed plane-staging re-reads were ALREADY L2-hit, so the residual
// lrh cost is (a) idx->pts latency chain at only 3 blocks/CU, (b) 2 barriers
// per 256-pt chunk, (c) staging bytes):
//  * planeT stored f16 (N(0,0.1) values; err budget ~1e-5 vs 4.9e-4 absmax):
//    LDS tile 46.6->23.3 KB, staging bytes halved.
//  * Intra-wave shuffle handoff: wave w's phase 1 computes slots
//    [base+64w,base+64w+64); phase 2 octet o step s needs point s*8+o of the
//    SAME wave -> 5 __shfl replace the s_* LDS arrays and BOTH barriers.
//    LDS total 23.3 KB -> ~6 blocks/CU (launch_bounds(256,5)); barrier-free
//    chunk loop doubles latency-hiding for the pts gather.
//  * Bijective XCD swizzle of cells (4096%8==0): each XCD owns a z-slab;
//    f16 plane working set ~1.4MB -> L2-resident.
//  * prep unchanged except plane transpose writes f16.

constexpr int kNPts   = 2000000;
constexpr int kReso   = 256;
constexpr int kPix    = kReso * kReso;        // 65536
constexpr int kCPlane = 12;                   // OUT_DIM(3) * RANK(4)
constexpr int kFReso  = 64;
constexpr int kNVox   = kFReso * kFReso * kFReso;  // 262144
constexpr int kFDim   = 32;
constexpr int kCellRes = 16;                  // bucket grid per axis
constexpr int kNCell  = kCellRes * kCellRes * kCellRes;  // 4096
constexpr int kCap    = 640;                  // slots per cell (mean 488)
constexpr unsigned kOvCap = 2000000u;         // overflow list (full N: can never drop)

constexpr int kThreads     = 256;             // lrh block size
constexpr int kPrepThreads = 1024;            // prep block size
constexpr int kPtsPerScB   = 16384;           // points per scatter block
constexpr int kScBlocks    = (kNPts + kPtsPerScB - 1) / kPtsPerScB;     // 123
constexpr int kPlaneBlocks = (3 * (kPix / 4)) / kPrepThreads;           // 48
constexpr int kFeatBlocks  = (kNVox / 4) / kPrepThreads;                // 64
constexpr int kPrepBlocks  = kScBlocks + kPlaneBlocks + kFeatBlocks;    // 235
constexpr int kOvBlocks    = 16;

constexpr int kStage = 18;                    // staged rows/cols per plane region
constexpr int kRowU2 = kStage * 3;            // 54 uint2 (8B) per staged row (18px*24B)

static __device__ __forceinline__ float clampf(float v, float lo, float hi) {
  return fminf(fmaxf(v, lo), hi);
}

static __device__ __forceinline__ float4 f4_scale_add(float4 v, float s, float4 acc) {
  acc.x = fmaf(v.x, s, acc.x);
  acc.y = fmaf(v.y, s, acc.y);
  acc.z = fmaf(v.z, s, acc.z);
  acc.w = fmaf(v.w, s, acc.w);
  return acc;
}

// 4 halfs packed in a uint2 -> float4
static __device__ __forceinline__ float4 h4(uint2 u) {
  __half2 a = *(__half2*)&u.x;
  __half2 b = *(__half2*)&u.y;
  float2 fa = __half22float2(a);
  float2 fb = __half22float2(b);
  return make_float4(fa.x, fa.y, fb.x, fb.y);
}

static __device__ __forceinline__ int cell_of(float x, float y, float z) {
  int xq = min(kCellRes - 1, max(0, (int)((x + 1.0f) * (0.5f * kCellRes))));
  int yq = min(kCellRes - 1, max(0, (int)((y + 1.0f) * (0.5f * kCellRes))));
  int zq = min(kCellRes - 1, max(0, (int)((z + 1.0f) * (0.5f * kCellRes))));
  return (zq * kCellRes + yq) * kCellRes + xq;
}

// Bilinear sample of f16 transposed plane [256,256,12] from GLOBAL (overflow path).
static __device__ __forceinline__ void sample_plane_trh(
    const __half* __restrict__ plane, float cx, float cy, float4 r[3]) {
  float x = clampf((cx + 1.0f) * 0.5f * (float)(kReso - 1), 0.0f, (float)(kReso - 1));
  float y = clampf((cy + 1.0f) * 0.5f * (float)(kReso - 1), 0.0f, (float)(kReso - 1));
  float fx0 = fminf(floorf(x), (float)(kReso - 2));
  float fy0 = fminf(floorf(y), (float)(kReso - 2));
  int x0 = (int)fx0;
  int y0 = (int)fy0;
  float wx = x - fx0;
  float wy = y - fy0;
  float w00 = (1.0f - wx) * (1.0f - wy);
  float w01 = wx * (1.0f - wy);
  float w10 = (1.0f - wx) * wy;
  float w11 = wx * wy;
  const uint2* v00 = (const uint2*)(plane + (size_t)(y0 * kReso + x0) * kCPlane);
  const uint2* v01 = (const uint2*)(plane + (size_t)(y0 * kReso + x0 + 1) * kCPlane);
  const uint2* v10 = (const uint2*)(plane + (size_t)((y0 + 1) * kReso + x0) * kCPlane);
  const uint2* v11 = (const uint2*)(plane + (size_t)((y0 + 1) * kReso + x0 + 1) * kCPlane);
#pragma unroll
  for (int i = 0; i < 3; ++i) {
    float4 acc = make_float4(0.f, 0.f, 0.f, 0.f);
    acc = f4_scale_add(h4(v00[i]), w00, acc);
    acc = f4_scale_add(h4(v01[i]), w01, acc);
    acc = f4_scale_add(h4(v10[i]), w10, acc);
    acc = f4_scale_add(h4(v11[i]), w11, acc);
    r[i] = acc;
  }
}

// Bilinear from LDS-staged f16 [18][18][12] region (uint2-packed).
static __device__ __forceinline__ void bilin_lds_h(
    const uint2* __restrict__ sp, int lc, int lr, float wc, float wr, float4 r[3]) {
  const uint2* t00 = sp + (lr * kStage + lc) * 3;
  const uint2* t01 = t00 + 3;
  const uint2* t10 = t00 + kRowU2;
  const uint2* t11 = t10 + 3;
  float w00 = (1.0f - wc) * (1.0f - wr);
  float w01 = wc * (1.0f - wr);
  float w10 = (1.0f - wc) * wr;
  float w11 = wc * wr;
#pragma unroll
  for (int i = 0; i < 3; ++i) {
    float4 acc = make_float4(0.f, 0.f, 0.f, 0.f);
    acc = f4_scale_add(h4(t00[i]), w00, acc);
    acc = f4_scale_add(h4(t01[i]), w01, acc);
    acc = f4_scale_add(h4(t10[i]), w10, acc);
    acc = f4_scale_add(h4(t11[i]), w11, acc);
    r[i] = acc;
  }
}

// ---------------- fused prep: two-pass bucket scatter + both transposes ----------------

__global__ __launch_bounds__(1024) void prep_fused(
    const float* __restrict__ pts,
    const float* __restrict__ p0, const float* __restrict__ p1,
    const float* __restrict__ p2, const float* __restrict__ featSrc,
    __half* __restrict__ planeTh, float* __restrict__ featT,
    unsigned* __restrict__ counts, unsigned* __restrict__ ovcnt,
    unsigned* __restrict__ ovlist, unsigned* __restrict__ buckets) {
  __shared__ unsigned short s_cellid[kPtsPerScB];  // 32 KB
  __shared__ unsigned s_hist[kNCell];              // 16 KB (count -> block base)
  __shared__ unsigned s_loc[kNCell];               // 16 KB (local rank)

  int b = blockIdx.x;
  int tid = threadIdx.x;

  if (b < kScBlocks) {
    // ---- block-local two-pass counting scatter over 16K points ----
    for (int i = tid; i < kNCell; i += kPrepThreads) s_hist[i] = 0u;
    __syncthreads();

    size_t base = (size_t)b * kPtsPerScB;
    for (int k = 0; k < kPtsPerScB / kPrepThreads; ++k) {
      int sl = k * kPrepThreads + tid;
      size_t g = base + sl;
      unsigned short cid = 0xFFFFu;
      if (g < (size_t)kNPts) {
        const float* pp = pts + 3 * g;
        cid = (unsigned short)cell_of(pp[0], pp[1], pp[2]);
        atomicAdd(&s_hist[cid], 1u);
      }
      s_cellid[sl] = cid;
    }
    __syncthreads();

    for (int c = tid; c < kNCell; c += kPrepThreads) {
      unsigned h = s_hist[c];
      s_loc[c] = 0u;
      s_hist[c] = h ? atomicAdd(&counts[c], h) : 0u;
    }
    __syncthreads();

    for (int k = 0; k < kPtsPerScB / kPrepThreads; ++k) {
      int sl = k * kPrepThreads + tid;
      unsigned short cid = s_cellid[sl];
      if (cid == 0xFFFFu) continue;
      unsigned r = atomicAdd(&s_loc[cid], 1u);
      unsigned pos = s_hist[cid] + r;
      unsigned idx = (unsigned)(base + sl);
      if (pos < (unsigned)kCap) {
        buckets[(size_t)cid * kCap + pos] = idx;
      } else {
        unsigned op = atomicAdd(ovcnt, 1u);
        if (op < kOvCap) ovlist[op] = idx;
      }
    }
  } else if (b < kScBlocks + kPlaneBlocks) {
    // --- 3 planes [12,256,256] -> planeTh (f16): 3 x [256,256,12]; 4 px/thread ---
    int t = (b - kScBlocks) * kPrepThreads + tid;
    constexpr int quarter = kPix / 4;  // 16384
    int p = t / quarter;
    int pix4 = (t % quarter) * 4;
    const float* src = (p == 0) ? p0 : (p == 1) ? p1 : p2;
    float4 v[kCPlane];
#pragma unroll
    for (int c = 0; c < kCPlane; ++c)
      v[c] = *(const float4*)(src + (size_t)c * kPix + pix4);
#pragma unroll
    for (int j = 0; j < 4; ++j) {
      float e[kCPlane];
#pragma unroll
      for (int c = 0; c < kCPlane; ++c) {
        const float* vc = (const float*)&v[c];
        e[c] = vc[j];
      }
      __half2* dst = (__half2*)(planeTh + ((size_t)(p * kPix + pix4) + j) * kCPlane);
#pragma unroll
      for (int h = 0; h < 6; ++h)
        dst[h] = __floats2half2_rn(e[2 * h], e[2 * h + 1]);
    }
  } else {
    // --- features [32,64,64,64] -> featT [64,64,64,32]; 4 vox/thread ---
    int t = (b - kScBlocks - kPlaneBlocks) * kPrepThreads + tid;
    int vox4 = t * 4;
#pragma unroll
    for (int chunk = 0; chunk < 4; ++chunk) {
      float4 v[8];
#pragma unroll
      for (int c8 = 0; c8 < 8; ++c8) {
        int c = chunk * 8 + c8;
        v[c8] = *(const float4*)(featSrc + (size_t)c * kNVox + vox4);
      }
#pragma unroll
      for (int j = 0; j < 4; ++j) {
        float e[8];
#pragma unroll
        for (int c8 = 0; c8 < 8; ++c8) e[c8] = ((const float*)&v[c8])[j];
        float4* dst = (float4*)(featT + (size_t)(vox4 + j) * kFDim + chunk * 8);
        dst[0] = make_float4(e[0], e[1], e[2], e[3]);
        dst[1] = make_float4(e[4], e[5], e[6], e[7]);
      }
    }
  }
}

// ---------------- main kernel: one 16^3 cell per block ----------------

__global__ __launch_bounds__(256, 5) void lrh_cells(
    const float* __restrict__ pts, const __half* __restrict__ planeTh,
    const float* __restrict__ feat,
    const unsigned* __restrict__ counts, const unsigned* __restrict__ buckets,
    const unsigned* __restrict__ ovcnt, const unsigned* __restrict__ ovlist,
    float* __restrict__ out) {
  __shared__ uint2 s_plane[3][kStage * kRowU2];  // 3*972*8 = 23328 B (f16 packed)

  int braw = blockIdx.x;
  int tid = threadIdx.x;

  if (braw < kNCell) {
    // bijective XCD swizzle: each XCD gets a contiguous z-slab of cells
    int b = ((braw & 7) << 9) | (braw >> 3);
    int cellx = b & (kCellRes - 1);
    int celly = (b >> 4) & (kCellRes - 1);
    int cellz = b >> 8;
    int sx = min(cellx * 255 / 16, kReso - kStage);
    int sy = min(celly * 255 / 16, kReso - kStage);
    int sz = min(cellz * 255 / 16, kReso - kStage);
    // plane01: cols=x rows=y; plane02: cols=x rows=z; plane12: cols=y rows=z
    const int colS[3] = {sx, sx, sy};
    const int rowS[3] = {sy, sz, sz};

    // stage 3 f16 regions: 3*18 rows x 54 uint2
    for (int i = tid; i < 3 * kStage * kRowU2; i += kThreads) {
      int p = i / (kStage * kRowU2);
      int rem = i - p * (kStage * kRowU2);
      int r = rem / kRowU2;
      int q = rem - r * kRowU2;
      const __half* srcp = planeTh +
          ((size_t)p * kPix + (size_t)(rowS[p] + r) * kReso + colS[p]) * kCPlane;
      s_plane[p][r * kRowU2 + q] = *(const uint2*)(srcp + q * 4);
    }
    __syncthreads();

    unsigned craw = counts[b];
    int cnt = craw < (unsigned)kCap ? (int)craw : kCap;

    int lane = tid & 63;
    int oct = lane >> 3;          // 0..7 within wave
    int l4 = (lane & 7) * 4;      // channel offset

    for (int base = 0; base < cnt; base += kThreads) {
      // ---------- phase 1: per-lane plane sampling -> registers ----------
      int slot = base + tid;
      int n = -1;
      int ivox = 0;
      float wxo = 0.f, wyo = 0.f, wzo = 0.f;
      if (slot < cnt) {
        n = (int)buckets[(size_t)b * kCap + slot];
        const float* pp = pts + 3 * (size_t)n;
        float xx = pp[0], yy = pp[1], zz = pp[2];

        float px = clampf((xx + 1.0f) * 0.5f * (float)(kReso - 1), 0.0f, (float)(kReso - 1));
        float py = clampf((yy + 1.0f) * 0.5f * (float)(kReso - 1), 0.0f, (float)(kReso - 1));
        float pz = clampf((zz + 1.0f) * 0.5f * (float)(kReso - 1), 0.0f, (float)(kReso - 1));
        float fx0 = fminf(floorf(px), (float)(kReso - 2));
        float fy0 = fminf(floorf(py), (float)(kReso - 2));
        float fz0 = fminf(floorf(pz), (float)(kReso - 2));
        float wx = px - fx0, wy = py - fy0, wz = pz - fz0;
        int lx = min(max((int)fx0 - sx, 0), kStage - 2);
        int ly = min(max((int)fy0 - sy, 0), kStage - 2);
        int lz = min(max((int)fz0 - sz, 0), kStage - 2);

        float4 a[3], bb[3], c3[3];
        bilin_lds_h(s_plane[0], lx, ly, wx, wy, a);    // (x,y)
        bilin_lds_h(s_plane[1], lx, lz, wx, wz, bb);   // (x,z)
        bilin_lds_h(s_plane[2], ly, lz, wy, wz, c3);   // (y,z)

        float coord[3];
#pragma unroll
        for (int d = 0; d < 3; ++d) {
          float mx = a[d].x * bb[d].x * c3[d].x;
          float my = a[d].y * bb[d].y * c3[d].y;
          float mz = a[d].z * bb[d].z * c3[d].z;
          float mw = a[d].w * bb[d].w * c3[d].w;
          coord[d] = (mx + my) + (mz + mw);
        }

        float gx = clampf((coord[0] + 1.0f) * 0.5f * (float)(kFReso - 1), 0.0f, (float)(kFReso - 1));
        float gy = clampf((coord[1] + 1.0f) * 0.5f * (float)(kFReso - 1), 0.0f, (float)(kFReso - 1));
        float gz = clampf((coord[2] + 1.0f) * 0.5f * (float)(kFReso - 1), 0.0f, (float)(kFReso - 1));
        float gfx0 = fminf(floorf(gx), (float)(kFReso - 2));
        float gfy0 = fminf(floorf(gy), (float)(kFReso - 2));
        float gfz0 = fminf(floorf(gz), (float)(kFReso - 2));
        int ix0 = (int)gfx0;
        int iy0 = (int)gfy0;
        int iz0 = (int)gfz0;
        wxo = gx - gfx0;
        wyo = gy - gfy0;
        wzo = gz - gfz0;
        ivox = (iz0 * kFReso + iy0) * kFReso + ix0;
      }

      // ---------- phase 2: octet-cooperative gather, intra-wave shuffle ----------
      // point p_local = step*8+oct was computed by lane p_local of THIS wave.
#pragma unroll
      for (int step = 0; step < 8; ++step) {
        int pl = step * 8 + oct;
        int n2    = __shfl(n, pl);
        int vox   = __shfl(ivox, pl);
        float wx2 = __shfl(wxo, pl);
        float wy2 = __shfl(wyo, pl);
        float wz2 = __shfl(wzo, pl);
        if (n2 < 0) continue;
        float ux = 1.0f - wx2, uy = 1.0f - wy2, uz = 1.0f - wz2;

        const float* fb = feat + (size_t)vox * kFDim + l4;
        float4 t0 = *(const float4*)(fb);
        float4 t1 = *(const float4*)(fb + kFDim);
        float4 t2 = *(const float4*)(fb + kFReso * kFDim);
        float4 t3 = *(const float4*)(fb + kFReso * kFDim + kFDim);
        float4 t4 = *(const float4*)(fb + kFReso * kFReso * kFDim);
        float4 t5 = *(const float4*)(fb + kFReso * kFReso * kFDim + kFDim);
        float4 t6 = *(const float4*)(fb + kFReso * kFReso * kFDim + kFReso * kFDim);
        float4 t7 = *(const float4*)(fb + kFReso * kFReso * kFDim + kFReso * kFDim + kFDim);

        float a0 = uz * uy, a1 = uz * wy2, a2 = wz2 * uy, a3 = wz2 * wy2;
        float w0 = a0 * ux, w1 = a0 * wx2;
        float w2 = a1 * ux, w3 = a1 * wx2;
        float w4 = a2 * ux, w5 = a2 * wx2;
        float w6 = a3 * ux, w7 = a3 * wx2;

        float4 acc;
        acc.x = t0.x * w0; acc.y = t0.y * w0; acc.z = t0.z * w0; acc.w = t0.w * w0;
        acc = f4_scale_add(t1, w1, acc);
        acc = f4_scale_add(t2, w2, acc);
        acc = f4_scale_add(t3, w3, acc);
        acc = f4_scale_add(t4, w4, acc);
        acc = f4_scale_add(t5, w5, acc);
        acc = f4_scale_add(t6, w6, acc);
        acc = f4_scale_add(t7, w7, acc);

        *(float4*)(out + (size_t)n2 * kFDim + l4) = acc;
      }
    }
  } else {
    // ---------- overflow tail (expected ~0 points): per-lane full path ----------
    unsigned ov = *ovcnt;
    if (ov > kOvCap) ov = kOvCap;
    const __half* p01 = planeTh;
    const __half* p02 = planeTh + (size_t)kPix * kCPlane;
    const __half* p12 = planeTh + (size_t)2 * kPix * kCPlane;
    for (unsigned i = (unsigned)(braw - kNCell) * kThreads + tid; i < ov;
         i += (unsigned)kOvBlocks * kThreads) {
      int n = (int)ovlist[i];
      float cx = pts[3 * (size_t)n + 0];
      float cy = pts[3 * (size_t)n + 1];
      float cz = pts[3 * (size_t)n + 2];

      float4 a[3], bb[3], c3[3];
      sample_plane_trh(p01, cx, cy, a);
      sample_plane_trh(p02, cx, cz, bb);
      sample_plane_trh(p12, cy, cz, c3);

      float coord[3];
#pragma unroll
      for (int d = 0; d < 3; ++d) {
        float mx = a[d].x * bb[d].x * c3[d].x;
        float my = a[d].y * bb[d].y * c3[d].y;
        float mz = a[d].z * bb[d].z * c3[d].z;
        float mw = a[d].w * bb[d].w * c3[d].w;
        coord[d] = (mx + my) + (mz + mw);
      }

      float gx = clampf((coord[0] + 1.0f) * 0.5f * (float)(kFReso - 1), 0.0f, (float)(kFReso - 1));
      float gy = clampf((coord[1] + 1.0f) * 0.5f * (float)(kFReso - 1), 0.0f, (float)(kFReso - 1));
      float gz = clampf((coord[2] + 1.0f) * 0.5f * (float)(kFReso - 1), 0.0f, (float)(kFReso - 1));
      float fx0 = fminf(floorf(gx), (float)(kFReso - 2));
      float fy0 = fminf(floorf(gy), (float)(kFReso - 2));
      float fz0 = fminf(floorf(gz), (float)(kFReso - 2));
      int ix0 = (int)fx0;
      int iy0 = (int)fy0;
      int iz0 = (int)fz0;
      float wx = gx - fx0, wy = gy - fy0, wz = gz - fz0;

      float acc[kFDim];
#pragma unroll
      for (int c = 0; c < kFDim; ++c) acc[c] = 0.0f;
#pragma unroll
      for (int dz = 0; dz < 2; ++dz) {
        float fzw = dz ? wz : (1.0f - wz);
#pragma unroll
        for (int dy = 0; dy < 2; ++dy) {
          float fyw = dy ? wy : (1.0f - wy);
#pragma unroll
          for (int dx = 0; dx < 2; ++dx) {
            float w = fzw * fyw * (dx ? wx : (1.0f - wx));
            int vox = ((iz0 + dz) * kFReso + (iy0 + dy)) * kFReso + (ix0 + dx);
            const float4* v = (const float4*)(feat + (size_t)vox * kFDim);
#pragma unroll
            for (int k = 0; k < 8; ++k) {
              float4 t = v[k];
              acc[4 * k + 0] = fmaf(t.x, w, acc[4 * k + 0]);
              acc[4 * k + 1] = fmaf(t.y, w, acc[4 * k + 1]);
              acc[4 * k + 2] = fmaf(t.z, w, acc[4 * k + 2]);
              acc[4 * k + 3] = fmaf(t.w, w, acc[4 * k + 3]);
            }
          }
        }
      }
      float4* o = (float4*)(out + (size_t)n * kFDim);
#pragma unroll
      for (int k = 0; k < 8; ++k)
        o[k] = make_float4(acc[4 * k], acc[4 * k + 1], acc[4 * k + 2], acc[4 * k + 3]);
    }
  }
}

extern "C" void kernel_launch(void* const* d_in, const int* in_sizes, int n_in,
                              void* d_out, int out_size, void* d_ws, size_t ws_size,
                              hipStream_t stream) {
  const float* pts  = (const float*)d_in[0];
  const float* p01  = (const float*)d_in[1];
  const float* p02  = (const float*)d_in[2];
  const float* p12  = (const float*)d_in[3];
  const float* feat = (const float*)d_in[4];
  float* out = (float*)d_out;

  // workspace layout
  const size_t off_planeT  = 0;
  const size_t sz_planeT   = (size_t)3 * kPix * kCPlane * sizeof(__half);  // 4,718,592
  const size_t off_featT   = (off_planeT + sz_planeT + 255) & ~(size_t)255;
  const size_t sz_featT    = (size_t)kNVox * kFDim * sizeof(float);        // 33,554,432
  const size_t off_counts  = off_featT + sz_featT;
  const size_t sz_counts   = (size_t)kNCell * sizeof(unsigned);            // 16,384
  const size_t off_ovcnt   = off_counts + sz_counts;
  const size_t sz_ovcnt    = 256;
  const size_t off_ovlist  = off_ovcnt + sz_ovcnt;
  const size_t sz_ovlist   = (size_t)kOvCap * sizeof(unsigned);            // 8,000,000
  const size_t off_buckets = off_ovlist + sz_ovlist;
  const size_t sz_buckets  = (size_t)kNCell * kCap * sizeof(unsigned);     // 10,485,760
  const size_t need = off_buckets + sz_buckets;                            // ~56.8 MB

  if (ws_size < need) return;

  char* wsb = (char*)d_ws;
  __half*   planeTh = (__half*)(wsb + off_planeT);
  float*    featT   = (float*)(wsb + off_featT);
  unsigned* counts  = (unsigned*)(wsb + off_counts);
  unsigned* ovcnt   = (unsigned*)(wsb + off_ovcnt);
  unsigned* ovlist  = (unsigned*)(wsb + off_ovlist);
  unsigned* buckets = (unsigned*)(wsb + off_buckets);

  hipMemsetAsync(counts, 0, sz_counts + sz_ovcnt, stream);
  hipLaunchKernelGGL(prep_fused, dim3(kPrepBlocks), dim3(kPrepThreads), 0, stream,
                     pts, p01, p02, p12, feat, planeTh, featT,
                     counts, ovcnt, ovlist, buckets);
  hipLaunchKernelGGL(lrh_cells, dim3(kNCell + kOvBlocks), dim3(kThreads), 0, stream,
                     pts, planeTh, featT, counts, buckets, ovcnt, ovlist, out);
}